// Round 15
// baseline (498.328 us; speedup 1.0000x reference)
//
#include <hip/hip_runtime.h>
#include <hip/hip_bf16.h>
#include <cstddef>

#define NN 50000
#define EE 800000
#define NB ((NN + 255) / 256)

typedef __attribute__((ext_vector_type(8))) short short8;
typedef __attribute__((ext_vector_type(4))) float f32x4;

#define GLB __attribute__((address_space(1)))
#define LDS __attribute__((address_space(3)))

__device__ __forceinline__ float leaky(float x) { return x >= 0.f ? x : 0.2f * x; }
__device__ __forceinline__ float bf2f(unsigned short u) {
  return __uint_as_float(((unsigned int)u) << 16);
}
__device__ __forceinline__ float bflo(unsigned int v) { return __uint_as_float(v << 16); }
__device__ __forceinline__ float bfhi(unsigned int v) { return __uint_as_float(v & 0xFFFF0000u); }
__device__ __forceinline__ unsigned short f2bf(float f) {
  __hip_bfloat16 b = __float2bfloat16(f);
  return __builtin_bit_cast(unsigned short, b);
}
__device__ __forceinline__ void accum8(float a, uint4 v, float* acc) {
  acc[0] += a * bflo(v.x); acc[1] += a * bfhi(v.x);
  acc[2] += a * bflo(v.y); acc[3] += a * bfhi(v.y);
  acc[4] += a * bflo(v.z); acc[5] += a * bfhi(v.z);
  acc[6] += a * bflo(v.w); acc[7] += a * bfhi(v.w);
}

// ==== bf16 MFMA GEMM + fused attention-logit epilogue =======================
// Staging via global_load_lds(16B) with k-segment XOR swizzle (round 14).
__global__ __launch_bounds__(256) void gemm_bf16_k(const unsigned short* __restrict__ A,
                                                   const unsigned short* __restrict__ Bt,
                                                   unsigned short* __restrict__ Cb,
                                                   int K, int Nfull,
                                                   const float* __restrict__ a_s,
                                                   const float* __restrict__ a_d,
                                                   float* __restrict__ als,
                                                   float* __restrict__ ald,
                                                   float* __restrict__ selfex) {
  __shared__ __align__(16) unsigned short As[128 * 32];  // 8 KB
  __shared__ __align__(16) unsigned short Bs[64 * 32];   // 4 KB
  const int tid = threadIdx.x;
  const int lane = tid & 63;
  const int w = tid >> 6;
  const int bm = blockIdx.x * 128;
  const int bn = blockIdx.y * 64;
  const int quad = lane >> 4;
  const int l16 = lane & 15;
  const int lrow = lane >> 2;
  const int lseg = lane & 3;
  f32x4 acc[2][4] = {};
  for (int kc = 0; kc < K; kc += 32) {
#pragma unroll
    for (int c = 0; c < 2; ++c) {
      int row = w * 32 + c * 16 + lrow;
      int g = lseg ^ ((row >> 2) & 3);
      int sr = bm + row; if (sr >= NN) sr = NN - 1;
      const unsigned short* gp = A + (size_t)sr * K + kc + g * 8;
      __builtin_amdgcn_global_load_lds((const GLB void*)gp,
                                       (LDS void*)&As[(w * 32 + c * 16) * 32], 16, 0, 0);
    }
    {
      int row = w * 16 + lrow;
      int g = lseg ^ ((row >> 2) & 3);
      const unsigned short* gp = Bt + (size_t)(bn + row) * K + kc + g * 8;
      __builtin_amdgcn_global_load_lds((const GLB void*)gp,
                                       (LDS void*)&Bs[(w * 16) * 32], 16, 0, 0);
    }
    __syncthreads();
    const int ra0 = w * 32 + l16;
    const int ra1 = ra0 + 16;
    short8 afr0 = *(const short8*)&As[ra0 * 32 + ((quad ^ ((ra0 >> 2) & 3)) << 3)];
    short8 afr1 = *(const short8*)&As[ra1 * 32 + ((quad ^ ((ra1 >> 2) & 3)) << 3)];
#pragma unroll
    for (int nt = 0; nt < 4; ++nt) {
      int rb = nt * 16 + l16;
      short8 bfr = *(const short8*)&Bs[rb * 32 + ((quad ^ ((rb >> 2) & 3)) << 3)];
      acc[0][nt] = __builtin_amdgcn_mfma_f32_16x16x32_bf16(afr0, bfr, acc[0][nt], 0, 0, 0);
      acc[1][nt] = __builtin_amdgcn_mfma_f32_16x16x32_bf16(afr1, bfr, acc[1][nt], 0, 0, 0);
    }
    __syncthreads();
  }
  const int head = bn >> 6;
  const int Hmul = Nfull >> 6;
  float vs[2][4] = {};
  float vd[2][4] = {};
#pragma unroll
  for (int nt = 0; nt < 4; ++nt) {
    const float asv = a_s[head * 64 + nt * 16 + l16];
    const float adv = a_d[head * 64 + nt * 16 + l16];
#pragma unroll
    for (int mt = 0; mt < 2; ++mt)
#pragma unroll
      for (int reg = 0; reg < 4; ++reg) {
        unsigned short c = f2bf(acc[mt][nt][reg]);
        int r = bm + w * 32 + mt * 16 + quad * 4 + reg;
        if (r < NN) Cb[(size_t)r * Nfull + bn + nt * 16 + l16] = c;
        float hv = bf2f(c);
        vs[mt][reg] += hv * asv;
        vd[mt][reg] += hv * adv;
      }
  }
#pragma unroll
  for (int off = 1; off < 16; off <<= 1) {
#pragma unroll
    for (int mt = 0; mt < 2; ++mt)
#pragma unroll
      for (int reg = 0; reg < 4; ++reg) {
        vs[mt][reg] += __shfl_xor(vs[mt][reg], off, 64);
        vd[mt][reg] += __shfl_xor(vd[mt][reg], off, 64);
      }
  }
  if (l16 == 0) {
#pragma unroll
    for (int mt = 0; mt < 2; ++mt)
#pragma unroll
      for (int reg = 0; reg < 4; ++reg) {
        int r = bm + w * 32 + mt * 16 + quad * 4 + reg;
        if (r < NN) {
          als[(size_t)r * Hmul + head] = vs[mt][reg];
          ald[(size_t)r * Hmul + head] = vd[mt][reg];
          selfex[(size_t)r * Hmul + head] = __expf(leaky(vs[mt][reg] + vd[mt][reg]));
        }
      }
  }
}

// ================= CSR build (topology is layer-invariant) ==================
__global__ __launch_bounds__(256) void hist_k(const int* __restrict__ ei, int* deg) {
  int i = blockIdx.x * 256 + threadIdx.x;
  if (i < EE) atomicAdd(&deg[ei[EE + i]], 1);
}

__global__ __launch_bounds__(256) void scan1_k(const int* __restrict__ deg,
                                               int* __restrict__ incl,
                                               int* __restrict__ partial) {
  __shared__ int s[256];
  int t = threadIdx.x;
  int i = blockIdx.x * 256 + t;
  int v = (i < NN) ? deg[i] : 0;
  s[t] = v;
  __syncthreads();
  for (int off = 1; off < 256; off <<= 1) {
    int u = (t >= off) ? s[t - off] : 0;
    __syncthreads();
    s[t] += u;
    __syncthreads();
  }
  if (i < NN) incl[i] = s[t];
  if (t == 255) partial[blockIdx.x] = s[255];
}

// merged scan2+scan3: every block redoes the tiny 196-entry partial scan
__global__ __launch_bounds__(256) void scan23_k(const int* __restrict__ deg,
                                                const int* __restrict__ incl,
                                                const int* __restrict__ partial,
                                                int* __restrict__ rowptr,
                                                int* __restrict__ cursor) {
  __shared__ int s[256];
  __shared__ int ex[256];
  int t = threadIdx.x;
  int v = (t < NB) ? partial[t] : 0;
  s[t] = v;
  __syncthreads();
  for (int off = 1; off < 256; off <<= 1) {
    int u = (t >= off) ? s[t - off] : 0;
    __syncthreads();
    s[t] += u;
    __syncthreads();
  }
  ex[t] = s[t] - v;  // exclusive
  __syncthreads();
  int base = ex[blockIdx.x];
  int i = blockIdx.x * 256 + t;
  if (i < NN) {
    int r = base + incl[i] - deg[i];
    rowptr[i] = r;
    cursor[i] = r;
  }
}

__global__ __launch_bounds__(256) void scatter_k(const int* __restrict__ ei,
                                                 int* __restrict__ cursor,
                                                 int* __restrict__ csr_src) {
  int i = blockIdx.x * 256 + threadIdx.x;
  if (i >= EE) return;
  int d = ei[EE + i];
  int p = atomicAdd(&cursor[d], 1);
  csr_src[p] = ei[i];
}

// ====== XCD-sliced gather-aggregate, H=4: slice = one head = 128B line ======
// Grid = grp*4 + sl; blockIdx%8 round-robin puts slice sl on XCDs {sl, sl+4},
// so each XCD's h working set is 50000x128B = 6.4MB (vs 25.6MB un-sliced).
// Slices are full 128B cache lines (round 8's sub-line mistake fixed) and
// alpha is inline (no ex re-read — round 8's other mistake). Wave = 1 dst:
// 8 edge-slots x 8 lanes x 16B; 8 edges in flight. Zero atomics.
__global__ __launch_bounds__(256) void aggr4s_k(const int* __restrict__ rowptr,
                                                const int* __restrict__ deg,
                                                const int* __restrict__ csr_src,
                                                const float* __restrict__ als,
                                                const float* __restrict__ ald,
                                                const float* __restrict__ selfex,
                                                const uint4* __restrict__ hb4,
                                                const float* __restrict__ bias,
                                                uint4* __restrict__ out4) {
  const int sl = blockIdx.x & 3;          // slice == head
  const int grp = blockIdx.x >> 2;
  const int dst = grp * 4 + (threadIdx.x >> 6);
  const int lane = threadIdx.x & 63;
  const int slot = lane >> 3;
  const int c8 = lane & 7;
  const int rs = rowptr[dst];
  const int dg = deg[dst];
  const float aldv = ald[dst * 4 + sl];

  float acc[8] = {};
  float dsum = 0.f;
  if (slot == 0) {  // self-loop (unnormalized); 8 c8-lanes cover the slice
    float a = selfex[dst * 4 + sl];
    dsum += a;
    uint4 v = hb4[(size_t)dst * 32 + sl * 8 + c8];
    accum8(a, v, acc);
  }
  for (int j = slot; j < dg; j += 8) {
    int s = csr_src[rs + j];
    float e = als[s * 4 + sl];
    uint4 v = hb4[(size_t)s * 32 + sl * 8 + c8];
    float a = __expf(leaky(e + aldv));
    dsum += a;
    accum8(a, v, acc);
  }
#pragma unroll
  for (int k = 0; k < 8; ++k) {
    acc[k] += __shfl_xor(acc[k], 8, 64);
    acc[k] += __shfl_xor(acc[k], 16, 64);
    acc[k] += __shfl_xor(acc[k], 32, 64);
  }
  dsum += __shfl_xor(dsum, 8, 64);
  dsum += __shfl_xor(dsum, 16, 64);
  dsum += __shfl_xor(dsum, 32, 64);
  if (slot == 0) {  // channels [sl*64 + c8*8, +8), relu (both H=4 layers)
    const float inv = 1.f / (dsum + 1e-16f);
    const float4 bz0 = *(const float4*)(bias + sl * 64 + c8 * 8);
    const float4 bz1 = *(const float4*)(bias + sl * 64 + c8 * 8 + 4);
    float c0, c1;
    uint4 o;
    c0 = fmaxf(acc[0] * inv + bz0.x, 0.f); c1 = fmaxf(acc[1] * inv + bz0.y, 0.f);
    o.x = ((unsigned int)f2bf(c1) << 16) | f2bf(c0);
    c0 = fmaxf(acc[2] * inv + bz0.z, 0.f); c1 = fmaxf(acc[3] * inv + bz0.w, 0.f);
    o.y = ((unsigned int)f2bf(c1) << 16) | f2bf(c0);
    c0 = fmaxf(acc[4] * inv + bz1.x, 0.f); c1 = fmaxf(acc[5] * inv + bz1.y, 0.f);
    o.z = ((unsigned int)f2bf(c1) << 16) | f2bf(c0);
    c0 = fmaxf(acc[6] * inv + bz1.z, 0.f); c1 = fmaxf(acc[7] * inv + bz1.w, 0.f);
    o.w = ((unsigned int)f2bf(c1) << 16) | f2bf(c0);
    out4[(size_t)dst * 32 + sl * 8 + c8] = o;
  }
}

// ====== gather-aggregate, inline alpha + den-sum, H=1 (round-12, row=128B) ==
__global__ __launch_bounds__(256) void aggr1c_k(const int* __restrict__ rowptr,
                                                const int* __restrict__ deg,
                                                const int* __restrict__ csr_src,
                                                const float* __restrict__ als,
                                                const float* __restrict__ ald,
                                                const float* __restrict__ selfex,
                                                const uint4* __restrict__ hb4,
                                                const float* __restrict__ bias,
                                                float* __restrict__ out) {
  const int dst = blockIdx.x * 4 + (threadIdx.x >> 6);
  const int lane = threadIdx.x & 63;
  const int slot = lane >> 3;
  const int c8 = lane & 7;
  const int rs = rowptr[dst];
  const int dg = deg[dst];
  const float aldv = ald[dst];

  float acc[8] = {};
  float dsum = 0.f;
  if (slot == 0) {
    float a = selfex[dst];
    dsum += a;
    uint4 v = hb4[(size_t)dst * 8 + c8];
    accum8(a, v, acc);
  }
  for (int j = slot; j < dg; j += 8) {
    int s = csr_src[rs + j];
    float e = als[s];
    uint4 v = hb4[(size_t)s * 8 + c8];
    float a = __expf(leaky(e + aldv));
    dsum += a;
    accum8(a, v, acc);
  }
#pragma unroll
  for (int k = 0; k < 8; ++k) {
    acc[k] += __shfl_xor(acc[k], 8, 64);
    acc[k] += __shfl_xor(acc[k], 16, 64);
    acc[k] += __shfl_xor(acc[k], 32, 64);
  }
  dsum += __shfl_xor(dsum, 8, 64);
  dsum += __shfl_xor(dsum, 16, 64);
  dsum += __shfl_xor(dsum, 32, 64);
  if (slot == 0) {  // no relu on layer 2; fp32 out
    const float inv = 1.f / (dsum + 1e-16f);
    const float4 bz0 = *(const float4*)(bias + c8 * 8);
    const float4 bz1 = *(const float4*)(bias + c8 * 8 + 4);
    float4 o0 = make_float4(acc[0] * inv + bz0.x, acc[1] * inv + bz0.y,
                            acc[2] * inv + bz0.z, acc[3] * inv + bz0.w);
    float4 o1 = make_float4(acc[4] * inv + bz1.x, acc[5] * inv + bz1.y,
                            acc[6] * inv + bz1.z, acc[7] * inv + bz1.w);
    *(float4*)(out + (size_t)dst * 64 + c8 * 8) = o0;
    *(float4*)(out + (size_t)dst * 64 + c8 * 8 + 4) = o1;
  }
}

// ---- fused prep: x cast + 3 weight transposes + deg zero + g zero ----------
__global__ __launch_bounds__(256) void prep_k(const float2* __restrict__ x2,
                                              unsigned int* __restrict__ xb_u,
                                              const float* __restrict__ W0,
                                              unsigned short* __restrict__ W0t,
                                              const float* __restrict__ W1,
                                              unsigned short* __restrict__ W1t,
                                              const float* __restrict__ W2,
                                              unsigned short* __restrict__ W2t,
                                              int* __restrict__ deg,
                                              float* __restrict__ g) {
  int bid = blockIdx.x;
  int tid = threadIdx.x;
  if (bid < 12500) {  // castx: NN*128/2 = 3.2M uints
    int i = bid * 256 + tid;
    float2 v = x2[i];
    xb_u[i] = ((unsigned int)f2bf(v.y) << 16) | f2bf(v.x);
    return;
  }
  if (bid < 12948) {  // weight transposes (448 blocks)
    int r = (bid - 12500) * 256 + tid;
    if (r < 32768) {            // W0t[256][128] <- W0[128][256]
      int n = r >> 7, k = r & 127;
      W0t[n * 128 + k] = f2bf(W0[k * 256 + n]);
    } else if (r < 98304) {     // W1t[256][256] <- W1[256][256]
      int rr = r - 32768;
      int n = rr >> 8, k = rr & 255;
      W1t[n * 256 + k] = f2bf(W1[k * 256 + n]);
    } else {                    // W2t[64][256] <- W2[256][64]
      int rr = r - 98304;
      int n = rr >> 8, k = rr & 255;
      W2t[n * 256 + k] = f2bf(W2[k * 64 + n]);
    }
    return;
  }
  if (bid < 13144) {  // deg zero (196 blocks)
    int i = (bid - 12948) * 256 + tid;
    if (i < NN) deg[i] = 0;
    return;
  }
  if (tid < 68) g[tid] = 0.f;  // g sums + counter
}

// ---- colsum + fused head: last block computes the final [1,64] output ------
__global__ __launch_bounds__(256) void colsum_head_k(const float* __restrict__ h2,
                                                     float* __restrict__ g,
                                                     unsigned int* __restrict__ cnt,
                                                     const float* __restrict__ hw,
                                                     const float* __restrict__ hb,
                                                     float* __restrict__ out) {
  __shared__ float s[256];
  __shared__ float sg[64];
  __shared__ unsigned int sdone;
  int tid = threadIdx.x;
  int c = tid & 63, rg = tid >> 6;
  float acc = 0.f;
  for (int n = blockIdx.x * 4 + rg; n < NN; n += gridDim.x * 4)
    acc += h2[n * 64 + c];
  s[tid] = acc;
  __syncthreads();
  if (tid < 64) atomicAdd(&g[c], s[c] + s[64 + c] + s[128 + c] + s[192 + c]);
  __threadfence();
  __syncthreads();
  if (tid == 0) sdone = atomicAdd(cnt, 1);
  __syncthreads();
  if (sdone != gridDim.x - 1) return;
  if (tid < 64) sg[tid] = atomicAdd(&g[tid], 0.f);  // coherent read
  __syncthreads();
  if (tid < 64) {
    const float invN = 1.0f / (float)NN;
    float a2 = hb[tid];
#pragma unroll 8
    for (int cc = 0; cc < 64; ++cc) a2 += sg[cc] * invN * hw[cc * 64 + tid];
    out[tid] = a2;
  }
}

extern "C" void kernel_launch(void* const* d_in, const int* in_sizes, int n_in,
                              void* d_out, int out_size, void* d_ws, size_t ws_size,
                              hipStream_t stream) {
  const float* x   = (const float*)d_in[0];
  const int*   ei  = (const int*)d_in[1];
  const float* W0  = (const float*)d_in[2];
  const float* a0s = (const float*)d_in[3];
  const float* a0d = (const float*)d_in[4];
  const float* b0  = (const float*)d_in[5];
  const float* W1  = (const float*)d_in[6];
  const float* a1s = (const float*)d_in[7];
  const float* a1d = (const float*)d_in[8];
  const float* b1  = (const float*)d_in[9];
  const float* W2  = (const float*)d_in[10];
  const float* a2s = (const float*)d_in[11];
  const float* a2d = (const float*)d_in[12];
  const float* b2  = (const float*)d_in[13];
  const float* hw  = (const float*)d_in[14];
  const float* hb  = (const float*)d_in[15];
  float* out = (float*)d_out;

  char* w = (char*)d_ws;
  unsigned short* xb   = (unsigned short*)w; w += (size_t)NN * 128 * 2;
  unsigned short* bufG = (unsigned short*)w; w += (size_t)NN * 256 * 2;
  unsigned short* bufA = (unsigned short*)w; w += (size_t)NN * 256 * 2;
  float* bufF = (float*)w;                   w += (size_t)NN * 64 * 4;
  unsigned short* W0t = (unsigned short*)w;  w += 256 * 128 * 2;
  unsigned short* W1t = (unsigned short*)w;  w += 256 * 256 * 2;
  unsigned short* W2t = (unsigned short*)w;  w += 64 * 256 * 2;
  float* als  = (float*)w;    w += (size_t)NN * 4 * 4;
  float* ald  = (float*)w;    w += (size_t)NN * 4 * 4;
  float* sfx  = (float*)w;    w += (size_t)NN * 4 * 4;
  int* deg     = (int*)w;     w += (size_t)NN * 4;
  int* rowptr  = (int*)w;     w += (size_t)NN * 4;
  int* cursor  = (int*)w;     w += (size_t)NN * 4;
  int* incl    = (int*)w;     w += (size_t)NN * 4;
  int* partial = (int*)w;     w += 256 * 4;
  int* csr_src = (int*)w;     w += (size_t)EE * 4;
  float* g    = (float*)w;    w += 256;           // g[0..63] sums; cnt at g+64

  // ---- prep (also zeroes deg and g) must precede hist ----
  prep_k<<<13145, 256, 0, stream>>>((const float2*)x, (unsigned int*)xb,
                                    W0, W0t, W1, W1t, W2, W2t, deg, g);

  // ---- CSR build (shared by all 3 layers) ----
  hist_k<<<(EE + 255) / 256, 256, 0, stream>>>(ei, deg);
  scan1_k<<<NB, 256, 0, stream>>>(deg, incl, partial);
  scan23_k<<<NB, 256, 0, stream>>>(deg, incl, partial, rowptr, cursor);
  scatter_k<<<(EE + 255) / 256, 256, 0, stream>>>(ei, cursor, csr_src);

  const int GX = (NN + 127) / 128;
  const int GA = NN / 4;        // 12500 exact (aggr1c)
  const int GA4 = GA * 4;       // 50000: grp*4 + slice (aggr4s)

  auto layer4 = [&](const unsigned short* in, int K, const unsigned short* Wt,
                    const float* a_s, const float* a_d, const float* bias,
                    unsigned short* hbuf, unsigned short* obuf) {
    gemm_bf16_k<<<dim3(GX, 4), 256, 0, stream>>>(in, Wt, hbuf, K, 256,
                                                 a_s, a_d, als, ald, sfx);
    aggr4s_k<<<GA4, 256, 0, stream>>>(rowptr, deg, csr_src, als, ald, sfx,
                                      (const uint4*)hbuf, bias, (uint4*)obuf);
  };

  // layers 0 and 1 (H=4)
  layer4(xb, 128, W0t, a0s, a0d, b0, bufG, bufA);
  layer4(bufA, 256, W1t, a1s, a1d, b1, bufG, bufA);

  // layer 2 (H=1)
  gemm_bf16_k<<<dim3(GX, 1), 256, 0, stream>>>(bufA, W2t, bufG, 256, 64,
                                               a2s, a2d, als, ald, sfx);
  aggr1c_k<<<GA, 256, 0, stream>>>(rowptr, deg, csr_src, als, ald, sfx,
                                   (const uint4*)bufG, b2, bufF);

  // ---- mean + head (g zeroed by prep_k) ----
  colsum_head_k<<<256, 256, 0, stream>>>(bufF, g, (unsigned int*)(g + 64), hw, hb, out);
}

// Round 16
// 438.422 us; speedup vs baseline: 1.1366x; 1.1366x over previous
//
#include <hip/hip_runtime.h>
#include <hip/hip_bf16.h>
#include <cstddef>

#define NN 50000
#define EE 800000
#define NB ((NN + 255) / 256)

typedef __attribute__((ext_vector_type(8))) short short8;
typedef __attribute__((ext_vector_type(4))) float f32x4;

#define GLB __attribute__((address_space(1)))
#define LDS __attribute__((address_space(3)))

__device__ __forceinline__ float leaky(float x) { return x >= 0.f ? x : 0.2f * x; }
__device__ __forceinline__ float bf2f(unsigned short u) {
  return __uint_as_float(((unsigned int)u) << 16);
}
__device__ __forceinline__ float bflo(unsigned int v) { return __uint_as_float(v << 16); }
__device__ __forceinline__ float bfhi(unsigned int v) { return __uint_as_float(v & 0xFFFF0000u); }
__device__ __forceinline__ unsigned short f2bf(float f) {
  __hip_bfloat16 b = __float2bfloat16(f);
  return __builtin_bit_cast(unsigned short, b);
}
__device__ __forceinline__ void accum8(float a, uint4 v, float* acc) {
  acc[0] += a * bflo(v.x); acc[1] += a * bfhi(v.x);
  acc[2] += a * bflo(v.y); acc[3] += a * bfhi(v.y);
  acc[4] += a * bflo(v.z); acc[5] += a * bfhi(v.z);
  acc[6] += a * bflo(v.w); acc[7] += a * bfhi(v.w);
}

// ==== bf16 MFMA GEMM + fused attention-logit epilogue =======================
// BK=64 k-blocking: 24 MFMA per barrier pair (vs 12) to amortize the
// global_load_lds drain. LDS rows are 128B (64 shorts); seg XOR (row&7)
// swizzle applied at the GLOBAL fetch address keeps ds_read_b128 fragment
// reads at free 2-way aliasing.
__global__ __launch_bounds__(256) void gemm_bf16_k(const unsigned short* __restrict__ A,
                                                   const unsigned short* __restrict__ Bt,
                                                   unsigned short* __restrict__ Cb,
                                                   int K, int Nfull,
                                                   const float* __restrict__ a_s,
                                                   const float* __restrict__ a_d,
                                                   float* __restrict__ als,
                                                   float* __restrict__ ald,
                                                   float* __restrict__ selfex) {
  __shared__ __align__(16) unsigned short As[128 * 64];  // 16 KB
  __shared__ __align__(16) unsigned short Bs[64 * 64];   // 8 KB
  const int tid = threadIdx.x;
  const int lane = tid & 63;
  const int w = tid >> 6;
  const int bm = blockIdx.x * 128;
  const int bn = blockIdx.y * 64;
  const int quad = lane >> 4;
  const int l16 = lane & 15;
  const int lrow8 = lane >> 3;   // 0..7 row within an 8-row staging call
  const int lseg = lane & 7;     // 16B segment within a 128B row
  f32x4 acc[2][4] = {};
  for (int kc = 0; kc < K; kc += 64) {
    // ---- A tile 128x64 (16KB): 4 calls/wave, 8 rows each ----
#pragma unroll
    for (int c = 0; c < 4; ++c) {
      int row = w * 32 + c * 8 + lrow8;
      int g = lseg ^ (row & 7);
      int sr = bm + row; if (sr >= NN) sr = NN - 1;
      const unsigned short* gp = A + (size_t)sr * K + kc + g * 8;
      __builtin_amdgcn_global_load_lds((const GLB void*)gp,
                                       (LDS void*)&As[(w * 32 + c * 8) * 64], 16, 0, 0);
    }
    // ---- B tile 64x64 (8KB): 2 calls/wave ----
#pragma unroll
    for (int c = 0; c < 2; ++c) {
      int row = w * 16 + c * 8 + lrow8;
      int g = lseg ^ (row & 7);
      const unsigned short* gp = Bt + (size_t)(bn + row) * K + kc + g * 8;
      __builtin_amdgcn_global_load_lds((const GLB void*)gp,
                                       (LDS void*)&Bs[(w * 16 + c * 8) * 64], 16, 0, 0);
    }
    __syncthreads();
    const int ra0 = w * 32 + l16;
    const int ra1 = ra0 + 16;
#pragma unroll
    for (int kk = 0; kk < 2; ++kk) {
      const int ko = kk * 4;  // 32 elements = 4 segments
      short8 afr0 = *(const short8*)&As[ra0 * 64 + (((quad + ko) ^ (ra0 & 7)) << 3)];
      short8 afr1 = *(const short8*)&As[ra1 * 64 + (((quad + ko) ^ (ra1 & 7)) << 3)];
#pragma unroll
      for (int nt = 0; nt < 4; ++nt) {
        int rb = nt * 16 + l16;
        short8 bfr = *(const short8*)&Bs[rb * 64 + (((quad + ko) ^ (rb & 7)) << 3)];
        acc[0][nt] = __builtin_amdgcn_mfma_f32_16x16x32_bf16(afr0, bfr, acc[0][nt], 0, 0, 0);
        acc[1][nt] = __builtin_amdgcn_mfma_f32_16x16x32_bf16(afr1, bfr, acc[1][nt], 0, 0, 0);
      }
    }
    __syncthreads();
  }
  const int head = bn >> 6;
  const int Hmul = Nfull >> 6;
  float vs[2][4] = {};
  float vd[2][4] = {};
#pragma unroll
  for (int nt = 0; nt < 4; ++nt) {
    const float asv = a_s[head * 64 + nt * 16 + l16];
    const float adv = a_d[head * 64 + nt * 16 + l16];
#pragma unroll
    for (int mt = 0; mt < 2; ++mt)
#pragma unroll
      for (int reg = 0; reg < 4; ++reg) {
        unsigned short c = f2bf(acc[mt][nt][reg]);
        int r = bm + w * 32 + mt * 16 + quad * 4 + reg;
        if (r < NN) Cb[(size_t)r * Nfull + bn + nt * 16 + l16] = c;
        float hv = bf2f(c);
        vs[mt][reg] += hv * asv;
        vd[mt][reg] += hv * adv;
      }
  }
#pragma unroll
  for (int off = 1; off < 16; off <<= 1) {
#pragma unroll
    for (int mt = 0; mt < 2; ++mt)
#pragma unroll
      for (int reg = 0; reg < 4; ++reg) {
        vs[mt][reg] += __shfl_xor(vs[mt][reg], off, 64);
        vd[mt][reg] += __shfl_xor(vd[mt][reg], off, 64);
      }
  }
  if (l16 == 0) {
#pragma unroll
    for (int mt = 0; mt < 2; ++mt)
#pragma unroll
      for (int reg = 0; reg < 4; ++reg) {
        int r = bm + w * 32 + mt * 16 + quad * 4 + reg;
        if (r < NN) {
          als[(size_t)r * Hmul + head] = vs[mt][reg];
          ald[(size_t)r * Hmul + head] = vd[mt][reg];
          selfex[(size_t)r * Hmul + head] = __expf(leaky(vs[mt][reg] + vd[mt][reg]));
        }
      }
  }
}

// ================= CSR build (topology is layer-invariant) ==================
__global__ __launch_bounds__(256) void hist_k(const int* __restrict__ ei, int* deg) {
  int i = blockIdx.x * 256 + threadIdx.x;
  if (i < EE) atomicAdd(&deg[ei[EE + i]], 1);
}

__global__ __launch_bounds__(256) void scan1_k(const int* __restrict__ deg,
                                               int* __restrict__ incl,
                                               int* __restrict__ partial) {
  __shared__ int s[256];
  int t = threadIdx.x;
  int i = blockIdx.x * 256 + t;
  int v = (i < NN) ? deg[i] : 0;
  s[t] = v;
  __syncthreads();
  for (int off = 1; off < 256; off <<= 1) {
    int u = (t >= off) ? s[t - off] : 0;
    __syncthreads();
    s[t] += u;
    __syncthreads();
  }
  if (i < NN) incl[i] = s[t];
  if (t == 255) partial[blockIdx.x] = s[255];
}

// merged scan2+scan3: every block redoes the tiny 196-entry partial scan
__global__ __launch_bounds__(256) void scan23_k(const int* __restrict__ deg,
                                                const int* __restrict__ incl,
                                                const int* __restrict__ partial,
                                                int* __restrict__ rowptr,
                                                int* __restrict__ cursor) {
  __shared__ int s[256];
  __shared__ int ex[256];
  int t = threadIdx.x;
  int v = (t < NB) ? partial[t] : 0;
  s[t] = v;
  __syncthreads();
  for (int off = 1; off < 256; off <<= 1) {
    int u = (t >= off) ? s[t - off] : 0;
    __syncthreads();
    s[t] += u;
    __syncthreads();
  }
  ex[t] = s[t] - v;  // exclusive
  __syncthreads();
  int base = ex[blockIdx.x];
  int i = blockIdx.x * 256 + t;
  if (i < NN) {
    int r = base + incl[i] - deg[i];
    rowptr[i] = r;
    cursor[i] = r;
  }
}

__global__ __launch_bounds__(256) void scatter_k(const int* __restrict__ ei,
                                                 int* __restrict__ cursor,
                                                 int* __restrict__ csr_src) {
  int i = blockIdx.x * 256 + threadIdx.x;
  if (i >= EE) return;
  int d = ei[EE + i];
  int p = atomicAdd(&cursor[d], 1);
  csr_src[p] = ei[i];
}

// ====== gather-aggregate, inline alpha + inline den-sum, H=4 (round-12) =====
// 4 edge-slots x 16 lanes x 32B, 2-edge unroll. Measured floor: ~65us,
// FETCH = 8-XCD replication floor (209MB) at ~3.65 TB/s. Slicing below the
// 512B row trades fetch for VALU at a net loss (rounds 8/15). Zero atomics.
__global__ __launch_bounds__(256) void aggr4c_k(const int* __restrict__ rowptr,
                                                const int* __restrict__ deg,
                                                const int* __restrict__ csr_src,
                                                const float* __restrict__ als,
                                                const float* __restrict__ ald,
                                                const float* __restrict__ selfex,
                                                const uint4* __restrict__ hb4,
                                                const float* __restrict__ bias,
                                                uint4* __restrict__ out4) {
  const int dst = blockIdx.x * 4 + (threadIdx.x >> 6);
  const int lane = threadIdx.x & 63;
  const int slot = lane >> 4;
  const int l16 = lane & 15;
  const int head = l16 >> 2;
  const int rs = rowptr[dst];
  const int dg = deg[dst];
  const float aldv = ald[dst * 4 + head];

  float acc[16] = {};
  float dsum = 0.f;
  if (slot == 0) {  // self-loop (unnormalized)
    float a = selfex[dst * 4 + head];
    dsum += a;
    uint4 v0 = hb4[(size_t)dst * 32 + l16 * 2];
    uint4 v1 = hb4[(size_t)dst * 32 + l16 * 2 + 1];
    accum8(a, v0, acc);
    accum8(a, v1, acc + 8);
  }
  int j = slot;
  for (; j + 4 < dg; j += 8) {
    int s0 = csr_src[rs + j];
    int s1 = csr_src[rs + j + 4];
    float e0 = als[s0 * 4 + head];
    float e1 = als[s1 * 4 + head];
    uint4 va0 = hb4[(size_t)s0 * 32 + l16 * 2];
    uint4 vb0 = hb4[(size_t)s0 * 32 + l16 * 2 + 1];
    uint4 va1 = hb4[(size_t)s1 * 32 + l16 * 2];
    uint4 vb1 = hb4[(size_t)s1 * 32 + l16 * 2 + 1];
    float a0 = __expf(leaky(e0 + aldv));
    float a1 = __expf(leaky(e1 + aldv));
    dsum += a0 + a1;
    accum8(a0, va0, acc);
    accum8(a0, vb0, acc + 8);
    accum8(a1, va1, acc);
    accum8(a1, vb1, acc + 8);
  }
  for (; j < dg; j += 4) {
    int s0 = csr_src[rs + j];
    float e0 = als[s0 * 4 + head];
    uint4 va0 = hb4[(size_t)s0 * 32 + l16 * 2];
    uint4 vb0 = hb4[(size_t)s0 * 32 + l16 * 2 + 1];
    float a0 = __expf(leaky(e0 + aldv));
    dsum += a0;
    accum8(a0, va0, acc);
    accum8(a0, vb0, acc + 8);
  }
#pragma unroll
  for (int k = 0; k < 16; ++k) {
    acc[k] += __shfl_xor(acc[k], 16, 64);
    acc[k] += __shfl_xor(acc[k], 32, 64);
  }
  dsum += __shfl_xor(dsum, 16, 64);
  dsum += __shfl_xor(dsum, 32, 64);
  if (slot == 0) {  // channels [l16*16, l16*16+16), relu (both H=4 layers)
    const float inv = 1.f / (dsum + 1e-16f);
    const float* bz = bias + l16 * 16;
    uint4 o0, o1;
    float c0, c1;
    c0 = fmaxf(acc[0] * inv + bz[0], 0.f);   c1 = fmaxf(acc[1] * inv + bz[1], 0.f);
    o0.x = ((unsigned int)f2bf(c1) << 16) | f2bf(c0);
    c0 = fmaxf(acc[2] * inv + bz[2], 0.f);   c1 = fmaxf(acc[3] * inv + bz[3], 0.f);
    o0.y = ((unsigned int)f2bf(c1) << 16) | f2bf(c0);
    c0 = fmaxf(acc[4] * inv + bz[4], 0.f);   c1 = fmaxf(acc[5] * inv + bz[5], 0.f);
    o0.z = ((unsigned int)f2bf(c1) << 16) | f2bf(c0);
    c0 = fmaxf(acc[6] * inv + bz[6], 0.f);   c1 = fmaxf(acc[7] * inv + bz[7], 0.f);
    o0.w = ((unsigned int)f2bf(c1) << 16) | f2bf(c0);
    c0 = fmaxf(acc[8] * inv + bz[8], 0.f);   c1 = fmaxf(acc[9] * inv + bz[9], 0.f);
    o1.x = ((unsigned int)f2bf(c1) << 16) | f2bf(c0);
    c0 = fmaxf(acc[10] * inv + bz[10], 0.f); c1 = fmaxf(acc[11] * inv + bz[11], 0.f);
    o1.y = ((unsigned int)f2bf(c1) << 16) | f2bf(c0);
    c0 = fmaxf(acc[12] * inv + bz[12], 0.f); c1 = fmaxf(acc[13] * inv + bz[13], 0.f);
    o1.z = ((unsigned int)f2bf(c1) << 16) | f2bf(c0);
    c0 = fmaxf(acc[14] * inv + bz[14], 0.f); c1 = fmaxf(acc[15] * inv + bz[15], 0.f);
    o1.w = ((unsigned int)f2bf(c1) << 16) | f2bf(c0);
    out4[(size_t)dst * 32 + l16 * 2] = o0;
    out4[(size_t)dst * 32 + l16 * 2 + 1] = o1;
  }
}

// ====== gather-aggregate, inline alpha + den-sum, H=1 (round-12) ============
__global__ __launch_bounds__(256) void aggr1c_k(const int* __restrict__ rowptr,
                                                const int* __restrict__ deg,
                                                const int* __restrict__ csr_src,
                                                const float* __restrict__ als,
                                                const float* __restrict__ ald,
                                                const float* __restrict__ selfex,
                                                const uint4* __restrict__ hb4,
                                                const float* __restrict__ bias,
                                                float* __restrict__ out) {
  const int dst = blockIdx.x * 4 + (threadIdx.x >> 6);
  const int lane = threadIdx.x & 63;
  const int slot = lane >> 3;
  const int c8 = lane & 7;
  const int rs = rowptr[dst];
  const int dg = deg[dst];
  const float aldv = ald[dst];

  float acc[8] = {};
  float dsum = 0.f;
  if (slot == 0) {
    float a = selfex[dst];
    dsum += a;
    uint4 v = hb4[(size_t)dst * 8 + c8];
    accum8(a, v, acc);
  }
  for (int j = slot; j < dg; j += 8) {
    int s = csr_src[rs + j];
    float e = als[s];
    uint4 v = hb4[(size_t)s * 8 + c8];
    float a = __expf(leaky(e + aldv));
    dsum += a;
    accum8(a, v, acc);
  }
#pragma unroll
  for (int k = 0; k < 8; ++k) {
    acc[k] += __shfl_xor(acc[k], 8, 64);
    acc[k] += __shfl_xor(acc[k], 16, 64);
    acc[k] += __shfl_xor(acc[k], 32, 64);
  }
  dsum += __shfl_xor(dsum, 8, 64);
  dsum += __shfl_xor(dsum, 16, 64);
  dsum += __shfl_xor(dsum, 32, 64);
  if (slot == 0) {  // no relu on layer 2; fp32 out
    const float inv = 1.f / (dsum + 1e-16f);
    const float4 bz0 = *(const float4*)(bias + c8 * 8);
    const float4 bz1 = *(const float4*)(bias + c8 * 8 + 4);
    float4 o0 = make_float4(acc[0] * inv + bz0.x, acc[1] * inv + bz0.y,
                            acc[2] * inv + bz0.z, acc[3] * inv + bz0.w);
    float4 o1 = make_float4(acc[4] * inv + bz1.x, acc[5] * inv + bz1.y,
                            acc[6] * inv + bz1.z, acc[7] * inv + bz1.w);
    *(float4*)(out + (size_t)dst * 64 + c8 * 8) = o0;
    *(float4*)(out + (size_t)dst * 64 + c8 * 8 + 4) = o1;
  }
}

// ---- fused prep: x cast + 3 weight transposes + deg zero + g zero ----------
__global__ __launch_bounds__(256) void prep_k(const float2* __restrict__ x2,
                                              unsigned int* __restrict__ xb_u,
                                              const float* __restrict__ W0,
                                              unsigned short* __restrict__ W0t,
                                              const float* __restrict__ W1,
                                              unsigned short* __restrict__ W1t,
                                              const float* __restrict__ W2,
                                              unsigned short* __restrict__ W2t,
                                              int* __restrict__ deg,
                                              float* __restrict__ g) {
  int bid = blockIdx.x;
  int tid = threadIdx.x;
  if (bid < 12500) {  // castx: NN*128/2 = 3.2M uints
    int i = bid * 256 + tid;
    float2 v = x2[i];
    xb_u[i] = ((unsigned int)f2bf(v.y) << 16) | f2bf(v.x);
    return;
  }
  if (bid < 12948) {  // weight transposes (448 blocks)
    int r = (bid - 12500) * 256 + tid;
    if (r < 32768) {            // W0t[256][128] <- W0[128][256]
      int n = r >> 7, k = r & 127;
      W0t[n * 128 + k] = f2bf(W0[k * 256 + n]);
    } else if (r < 98304) {     // W1t[256][256] <- W1[256][256]
      int rr = r - 32768;
      int n = rr >> 8, k = rr & 255;
      W1t[n * 256 + k] = f2bf(W1[k * 256 + n]);
    } else {                    // W2t[64][256] <- W2[256][64]
      int rr = r - 98304;
      int n = rr >> 8, k = rr & 255;
      W2t[n * 256 + k] = f2bf(W2[k * 64 + n]);
    }
    return;
  }
  if (bid < 13144) {  // deg zero (196 blocks)
    int i = (bid - 12948) * 256 + tid;
    if (i < NN) deg[i] = 0;
    return;
  }
  if (tid < 68) g[tid] = 0.f;  // g sums + counter
}

// ---- colsum + fused head: last block computes the final [1,64] output ------
__global__ __launch_bounds__(256) void colsum_head_k(const float* __restrict__ h2,
                                                     float* __restrict__ g,
                                                     unsigned int* __restrict__ cnt,
                                                     const float* __restrict__ hw,
                                                     const float* __restrict__ hb,
                                                     float* __restrict__ out) {
  __shared__ float s[256];
  __shared__ float sg[64];
  __shared__ unsigned int sdone;
  int tid = threadIdx.x;
  int c = tid & 63, rg = tid >> 6;
  float acc = 0.f;
  for (int n = blockIdx.x * 4 + rg; n < NN; n += gridDim.x * 4)
    acc += h2[n * 64 + c];
  s[tid] = acc;
  __syncthreads();
  if (tid < 64) atomicAdd(&g[c], s[c] + s[64 + c] + s[128 + c] + s[192 + c]);
  __threadfence();
  __syncthreads();
  if (tid == 0) sdone = atomicAdd(cnt, 1);
  __syncthreads();
  if (sdone != gridDim.x - 1) return;
  if (tid < 64) sg[tid] = atomicAdd(&g[tid], 0.f);  // coherent read
  __syncthreads();
  if (tid < 64) {
    const float invN = 1.0f / (float)NN;
    float a2 = hb[tid];
#pragma unroll 8
    for (int cc = 0; cc < 64; ++cc) a2 += sg[cc] * invN * hw[cc * 64 + tid];
    out[tid] = a2;
  }
}

extern "C" void kernel_launch(void* const* d_in, const int* in_sizes, int n_in,
                              void* d_out, int out_size, void* d_ws, size_t ws_size,
                              hipStream_t stream) {
  const float* x   = (const float*)d_in[0];
  const int*   ei  = (const int*)d_in[1];
  const float* W0  = (const float*)d_in[2];
  const float* a0s = (const float*)d_in[3];
  const float* a0d = (const float*)d_in[4];
  const float* b0  = (const float*)d_in[5];
  const float* W1  = (const float*)d_in[6];
  const float* a1s = (const float*)d_in[7];
  const float* a1d = (const float*)d_in[8];
  const float* b1  = (const float*)d_in[9];
  const float* W2  = (const float*)d_in[10];
  const float* a2s = (const float*)d_in[11];
  const float* a2d = (const float*)d_in[12];
  const float* b2  = (const float*)d_in[13];
  const float* hw  = (const float*)d_in[14];
  const float* hb  = (const float*)d_in[15];
  float* out = (float*)d_out;

  char* w = (char*)d_ws;
  unsigned short* xb   = (unsigned short*)w; w += (size_t)NN * 128 * 2;
  unsigned short* bufG = (unsigned short*)w; w += (size_t)NN * 256 * 2;
  unsigned short* bufA = (unsigned short*)w; w += (size_t)NN * 256 * 2;
  float* bufF = (float*)w;                   w += (size_t)NN * 64 * 4;
  unsigned short* W0t = (unsigned short*)w;  w += 256 * 128 * 2;
  unsigned short* W1t = (unsigned short*)w;  w += 256 * 256 * 2;
  unsigned short* W2t = (unsigned short*)w;  w += 64 * 256 * 2;
  float* als  = (float*)w;    w += (size_t)NN * 4 * 4;
  float* ald  = (float*)w;    w += (size_t)NN * 4 * 4;
  float* sfx  = (float*)w;    w += (size_t)NN * 4 * 4;
  int* deg     = (int*)w;     w += (size_t)NN * 4;
  int* rowptr  = (int*)w;     w += (size_t)NN * 4;
  int* cursor  = (int*)w;     w += (size_t)NN * 4;
  int* incl    = (int*)w;     w += (size_t)NN * 4;
  int* partial = (int*)w;     w += 256 * 4;
  int* csr_src = (int*)w;     w += (size_t)EE * 4;
  float* g    = (float*)w;    w += 256;           // g[0..63] sums; cnt at g+64

  // ---- prep (also zeroes deg and g) must precede hist ----
  prep_k<<<13145, 256, 0, stream>>>((const float2*)x, (unsigned int*)xb,
                                    W0, W0t, W1, W1t, W2, W2t, deg, g);

  // ---- CSR build (shared by all 3 layers) ----
  hist_k<<<(EE + 255) / 256, 256, 0, stream>>>(ei, deg);
  scan1_k<<<NB, 256, 0, stream>>>(deg, incl, partial);
  scan23_k<<<NB, 256, 0, stream>>>(deg, incl, partial, rowptr, cursor);
  scatter_k<<<(EE + 255) / 256, 256, 0, stream>>>(ei, cursor, csr_src);

  const int GX = (NN + 127) / 128;
  const int GA = NN / 4;   // 12500 exact

  auto layer4 = [&](const unsigned short* in, int K, const unsigned short* Wt,
                    const float* a_s, const float* a_d, const float* bias,
                    unsigned short* hbuf, unsigned short* obuf) {
    gemm_bf16_k<<<dim3(GX, 4), 256, 0, stream>>>(in, Wt, hbuf, K, 256,
                                                 a_s, a_d, als, ald, sfx);
    aggr4c_k<<<GA, 256, 0, stream>>>(rowptr, deg, csr_src, als, ald, sfx,
                                     (const uint4*)hbuf, bias, (uint4*)obuf);
  };

  // layers 0 and 1 (H=4)
  layer4(xb, 128, W0t, a0s, a0d, b0, bufG, bufA);
  layer4(bufA, 256, W1t, a1s, a1d, b1, bufG, bufA);

  // layer 2 (H=1)
  gemm_bf16_k<<<dim3(GX, 1), 256, 0, stream>>>(bufA, W2t, bufG, 256, 64,
                                               a2s, a2d, als, ald, sfx);
  aggr1c_k<<<GA, 256, 0, stream>>>(rowptr, deg, csr_src, als, ald, sfx,
                                   (const uint4*)bufG, b2, bufF);

  // ---- mean + head (g zeroed by prep_k) ----
  colsum_head_k<<<256, 256, 0, stream>>>(bufF, g, (unsigned int*)(g + 64), hw, hb, out);
}